// Round 3
// baseline (809.009 us; speedup 1.0000x reference)
//
#include <hip/hip_runtime.h>

typedef __bf16 bf16x8_t __attribute__((ext_vector_type(8)));
typedef float  f32x4_t  __attribute__((ext_vector_type(4)));
typedef float  floatx4  __attribute__((ext_vector_type(4)));
typedef unsigned short ushortx4 __attribute__((ext_vector_type(4)));

__device__ __forceinline__ float bf2f(unsigned short u) {
    union { unsigned int i; float f; } c; c.i = ((unsigned int)u) << 16; return c.f;
}
__device__ __forceinline__ unsigned short f2bf(float f) {
    union { float f; unsigned int i; } c; c.f = f;
    unsigned int u = c.i;
    u += 0x7fffu + ((u >> 16) & 1u);   // RNE
    return (unsigned short)(u >> 16);
}

// ---------------------------------------------------------------------------
// GEMM: C(MxN) = A(MxK) @ W(KxN) + bias(N), fp32 weights/bias, fp32 acc.
// A is f32 (GEMM1: x) or bf16 (GEMM3: attn in ws); C is bf16 (ws) or f32 (out).
// Inputs converted to bf16 during LDS staging; 16x16x32 bf16 MFMA.
// 128x128 tile, BK=32, 4 waves x (4x4) 16x16 tiles.
// A staged [m][k] k-contig, W staged transposed [n][k] k-contig.
// ---------------------------------------------------------------------------
#define BM 128
#define BN 128
#define BK 32
#define LDT 40

template<bool A_F32, bool C_F32>
__global__ __launch_bounds__(256) void gemm_bias_kernel(
    const void* __restrict__ Ap, const float* __restrict__ W,
    const float* __restrict__ bias, void* __restrict__ Cp,
    int N, int K, int lda, int ldc)
{
    __shared__ __align__(16) unsigned short As[BM * LDT];
    __shared__ __align__(16) unsigned short Bs[BN * LDT];

    const int tid  = threadIdx.x;
    const int lane = tid & 63;
    const int wid  = tid >> 6;       // 0..3
    const int wm   = wid >> 1;       // 0..1
    const int wn   = wid & 1;        // 0..1
    const int quad = lane >> 4;      // 0..3
    const int lr   = lane & 15;      // 0..15

    const int m0 = blockIdx.y * BM;
    const int n0 = blockIdx.x * BN;

    f32x4_t acc[4][4];
#pragma unroll
    for (int i = 0; i < 4; ++i)
#pragma unroll
        for (int j = 0; j < 4; ++j)
            acc[i][j] = (f32x4_t){0.f, 0.f, 0.f, 0.f};

    for (int k0 = 0; k0 < K; k0 += BK) {
        // ---- stage A tile (128 rows x 32 k) as bf16 ----
        if (A_F32) {
            const float* A = (const float*)Ap;
#pragma unroll
            for (int it = 0; it < 4; ++it) {
                int q   = tid + it * 256;        // 0..1023 quads of 4 floats
                int row = q >> 3;                // 8 quads per 32-float row
                int col = (q & 7) * 4;
                floatx4 f = *reinterpret_cast<const floatx4*>(A + (size_t)(m0 + row) * lda + k0 + col);
                ushortx4 s;
                s.x = f2bf(f.x); s.y = f2bf(f.y); s.z = f2bf(f.z); s.w = f2bf(f.w);
                *reinterpret_cast<ushortx4*>(&As[row * LDT + col]) = s;
            }
        } else {
            const unsigned short* A = (const unsigned short*)Ap;
            int a_row = tid >> 2;                // 0..63
            int a_col = (tid & 3) * 8;           // 0,8,16,24
#pragma unroll
            for (int r = 0; r < 2; ++r) {
                int row = a_row + r * 64;
                uint4 u = *reinterpret_cast<const uint4*>(A + (size_t)(m0 + row) * lda + k0 + a_col);
                *reinterpret_cast<uint4*>(&As[row * LDT + a_col]) = u;
            }
        }
        // ---- stage W tile transposed: Bs[n][k], f32 source ----
#pragma unroll
        for (int it = 0; it < 4; ++it) {
            int q  = tid + it * 256;             // 0..1023 quads
            int kk = q >> 5;                     // 32 quads per 128-n k-row
            int nn = (q & 31) * 4;
            floatx4 f = *reinterpret_cast<const floatx4*>(W + (size_t)(k0 + kk) * N + n0 + nn);
            Bs[(nn + 0) * LDT + kk] = f2bf(f.x);
            Bs[(nn + 1) * LDT + kk] = f2bf(f.y);
            Bs[(nn + 2) * LDT + kk] = f2bf(f.z);
            Bs[(nn + 3) * LDT + kk] = f2bf(f.w);
        }
        __syncthreads();

        bf16x8_t av[4], bv[4];
#pragma unroll
        for (int i = 0; i < 4; ++i)
            av[i] = *reinterpret_cast<const bf16x8_t*>(&As[(wm * 64 + i * 16 + lr) * LDT + quad * 8]);
#pragma unroll
        for (int j = 0; j < 4; ++j)
            bv[j] = *reinterpret_cast<const bf16x8_t*>(&Bs[(wn * 64 + j * 16 + lr) * LDT + quad * 8]);

#pragma unroll
        for (int i = 0; i < 4; ++i)
#pragma unroll
            for (int j = 0; j < 4; ++j)
                acc[i][j] = __builtin_amdgcn_mfma_f32_16x16x32_bf16(av[i], bv[j], acc[i][j], 0, 0, 0);

        __syncthreads();
    }

    // epilogue: C/D layout col=lane&15, row=quad*4+reg
#pragma unroll
    for (int j = 0; j < 4; ++j) {
        int col = n0 + wn * 64 + j * 16 + lr;
        float bj = bias[col];
#pragma unroll
        for (int i = 0; i < 4; ++i) {
            int rbase = m0 + wm * 64 + i * 16 + quad * 4;
#pragma unroll
            for (int r = 0; r < 4; ++r) {
                float v = acc[i][j][r] + bj;
                size_t idx = (size_t)(rbase + r) * ldc + col;
                if (C_F32) ((float*)Cp)[idx] = v;
                else       ((unsigned short*)Cp)[idx] = f2bf(v);
            }
        }
    }
}

// ---------------------------------------------------------------------------
// Neighborhood attention 1D: one block per (b,l). K=13, H=16, D=64, L=4096.
// qkv ws (bf16) layout: [(b*L+l)][3*1024], q at +0, k at +1024, v at +2048.
// attn[bl] written IN PLACE into the q-slot: block bl is the only reader of
// q[bl] (staged to LDS first); cross-block reads touch only k/v slots.
// ---------------------------------------------------------------------------
#define NA_L 4096
#define NA_K 13
#define NA_H 16
#define NA_D 64
#define NA_SCALE 0.125f

__global__ __launch_bounds__(256) void na1d_kernel(
    unsigned short* qkv, const float* __restrict__ rpb)
{
    __shared__ float qs[NA_H * NA_D];      // 1024 scaled q
    __shared__ float wgt[NA_H][NA_K];      // logits -> weights

    const int bl = blockIdx.x;             // b*4096 + l
    const int b  = bl >> 12;
    const int l  = bl & 4095;
    int ni = l - 6;
    if (ni < 0) ni = 0;
    if (ni > NA_L - NA_K) ni = NA_L - NA_K;

    const int t = threadIdx.x;
    unsigned short* qrow = qkv + (size_t)bl * 3072;

    // load + scale q (4 elems/thread)
    {
        uint2 raw = *reinterpret_cast<const uint2*>(qrow + t * 4);
        qs[t * 4 + 0] = bf2f((unsigned short)(raw.x & 0xffff)) * NA_SCALE;
        qs[t * 4 + 1] = bf2f((unsigned short)(raw.x >> 16)) * NA_SCALE;
        qs[t * 4 + 2] = bf2f((unsigned short)(raw.y & 0xffff)) * NA_SCALE;
        qs[t * 4 + 3] = bf2f((unsigned short)(raw.y >> 16)) * NA_SCALE;
    }
    __syncthreads();

    // logits: 16 heads x 13 neighbors
    if (t < NA_H * NA_K) {
        int h = t / NA_K;
        int j = t - h * NA_K;
        const unsigned short* krow = qkv + (size_t)(b * NA_L + ni + j) * 3072 + 1024 + h * 64;
        const float* qh = &qs[h * 64];
        float s = 0.f;
#pragma unroll
        for (int d = 0; d < NA_D; d += 4) {
            uint2 kr = *reinterpret_cast<const uint2*>(krow + d);
            s += qh[d + 0] * bf2f((unsigned short)(kr.x & 0xffff));
            s += qh[d + 1] * bf2f((unsigned short)(kr.x >> 16));
            s += qh[d + 2] * bf2f((unsigned short)(kr.y & 0xffff));
            s += qh[d + 3] * bf2f((unsigned short)(kr.y >> 16));
        }
        int pi = ni - l + 12;
        s += rpb[h * 25 + pi + j];
        wgt[h][j] = s;
    }
    __syncthreads();

    // softmax per head
    if (t < NA_H) {
        float m = -1e30f;
#pragma unroll
        for (int j = 0; j < NA_K; ++j) m = fmaxf(m, wgt[t][j]);
        float sum = 0.f;
#pragma unroll
        for (int j = 0; j < NA_K; ++j) {
            float e = expf(wgt[t][j] - m);
            wgt[t][j] = e;
            sum += e;
        }
        float inv = 1.f / sum;
#pragma unroll
        for (int j = 0; j < NA_K; ++j) wgt[t][j] *= inv;
    }
    __syncthreads();

    // output: each thread does 4 dims of one head; write into own q-slot
    const int h  = t >> 4;
    const int d0 = (t & 15) * 4;
    float o0 = 0.f, o1 = 0.f, o2 = 0.f, o3 = 0.f;
#pragma unroll
    for (int j = 0; j < NA_K; ++j) {
        float w = wgt[h][j];
        const unsigned short* vrow = qkv + (size_t)(b * NA_L + ni + j) * 3072 + 2048 + h * 64 + d0;
        uint2 vr = *reinterpret_cast<const uint2*>(vrow);
        o0 += w * bf2f((unsigned short)(vr.x & 0xffff));
        o1 += w * bf2f((unsigned short)(vr.x >> 16));
        o2 += w * bf2f((unsigned short)(vr.y & 0xffff));
        o3 += w * bf2f((unsigned short)(vr.y >> 16));
    }
    uint2 packed;
    packed.x = (unsigned int)f2bf(o0) | ((unsigned int)f2bf(o1) << 16);
    packed.y = (unsigned int)f2bf(o2) | ((unsigned int)f2bf(o3) << 16);
    *reinterpret_cast<uint2*>(qrow + h * 64 + d0) = packed;
}

// ---------------------------------------------------------------------------
extern "C" void kernel_launch(void* const* d_in, const int* in_sizes, int n_in,
                              void* d_out, int out_size, void* d_ws, size_t ws_size,
                              hipStream_t stream)
{
    const float* x      = (const float*)d_in[0]; // (4,4096,1024) f32
    const float* w_qkv  = (const float*)d_in[1]; // (1024,3072)   f32
    const float* b_qkv  = (const float*)d_in[2]; // (3072,)       f32
    const float* rpb    = (const float*)d_in[3]; // (16,25)       f32
    const float* w_proj = (const float*)d_in[4]; // (1024,1024)   f32
    const float* b_proj = (const float*)d_in[5]; // (1024,)       f32
    float* out = (float*)d_out;                  // (4,4096,1024) f32

    const int M  = 4 * 4096;   // 16384
    const int K  = 1024;
    const int N1 = 3072;
    const int N2 = 1024;

    unsigned short* qkv = (unsigned short*)d_ws;   // M*N1 bf16 = 96 MiB

    // 1) qkv = bf16(x) @ bf16(w_qkv) + b_qkv   (A f32 stride 1024 -> C bf16 stride 3072)
    gemm_bias_kernel<true, false><<<dim3(N1 / BN, M / BM), 256, 0, stream>>>(
        x, w_qkv, b_qkv, qkv, N1, K, K, N1);
    // 2) neighborhood attention, attn written in place into q-slots (bf16)
    na1d_kernel<<<dim3(M), 256, 0, stream>>>(qkv, rpb);
    // 3) out = attn @ bf16(w_proj) + b_proj    (A bf16 stride 3072 -> C f32)
    gemm_bias_kernel<false, true><<<dim3(N2 / BN, M / BM), 256, 0, stream>>>(
        qkv, w_proj, b_proj, out, N2, K, N1, N2);
}

// Round 4
// 473.883 us; speedup vs baseline: 1.7072x; 1.7072x over previous
//
#include <hip/hip_runtime.h>

typedef __bf16 bf16x8_t __attribute__((ext_vector_type(8)));
typedef float  f32x4_t  __attribute__((ext_vector_type(4)));
typedef float  floatx4  __attribute__((ext_vector_type(4)));
typedef unsigned short ushortx4 __attribute__((ext_vector_type(4)));

__device__ __forceinline__ float bf2f(unsigned short u) {
    union { unsigned int i; float f; } c; c.i = ((unsigned int)u) << 16; return c.f;
}
__device__ __forceinline__ unsigned short f2bf(float f) {
    union { float f; unsigned int i; } c; c.f = f;
    unsigned int u = c.i;
    u += 0x7fffu + ((u >> 16) & 1u);   // RNE
    return (unsigned short)(u >> 16);
}

// ---------------------------------------------------------------------------
// Weight prep: Wt[n][k] (bf16) = W[k][n] (f32). 32x32 LDS-tiled transpose.
// ---------------------------------------------------------------------------
__global__ __launch_bounds__(256) void transpose_f32_to_bf16(
    const float* __restrict__ W, unsigned short* __restrict__ Wt,
    int Kdim, int Ndim)
{
    __shared__ float tile[32][33];
    const int n0 = blockIdx.x * 32, k0 = blockIdx.y * 32;
    const int tx = threadIdx.x & 31, ty = threadIdx.x >> 5;   // ty 0..7
#pragma unroll
    for (int r = 0; r < 4; ++r) {
        int k = ty + r * 8;
        tile[k][tx] = W[(size_t)(k0 + k) * Ndim + n0 + tx];
    }
    __syncthreads();
#pragma unroll
    for (int r = 0; r < 4; ++r) {
        int n = ty + r * 8;
        Wt[(size_t)(n0 + n) * Kdim + k0 + tx] = f2bf(tile[tx][n]);
    }
}

// ---------------------------------------------------------------------------
// GEMM: C(MxN) = A(MxK) @ W(KxN) + bias(N), fp32 acc, bf16 MFMA 16x16x32.
// A_F32: A is f32 (converted during staging) else bf16.
// C_F32: C stored f32 else bf16.
// BT:    W is pre-transposed bf16 [n][k] (fast; coalesced b128 staging)
//        else f32 [k][n] (fallback scatter staging).
// 128x128 tile, BK=32, 4 waves x (4x4) 16x16 tiles. LDS ld=40 shorts (80 B:
// staging writes & fragment reads both analyze to <=2-way conflicts = free).
// ---------------------------------------------------------------------------
#define BM 128
#define BN 128
#define BK 32
#define LDT 40

template<bool A_F32, bool C_F32, bool BT>
__global__ __launch_bounds__(256) void gemm_bias_kernel(
    const void* __restrict__ Ap, const void* __restrict__ Wp,
    const float* __restrict__ bias, void* __restrict__ Cp,
    int N, int K, int lda, int ldc)
{
    __shared__ __align__(16) unsigned short As[BM * LDT];
    __shared__ __align__(16) unsigned short Bs[BN * LDT];

    const int tid  = threadIdx.x;
    const int lane = tid & 63;
    const int wid  = tid >> 6;       // 0..3
    const int wm   = wid >> 1;       // 0..1
    const int wn   = wid & 1;        // 0..1
    const int quad = lane >> 4;      // 0..3
    const int lr   = lane & 15;      // 0..15

    const int m0 = blockIdx.y * BM;
    const int n0 = blockIdx.x * BN;

    f32x4_t acc[4][4];
#pragma unroll
    for (int i = 0; i < 4; ++i)
#pragma unroll
        for (int j = 0; j < 4; ++j)
            acc[i][j] = (f32x4_t){0.f, 0.f, 0.f, 0.f};

    for (int k0 = 0; k0 < K; k0 += BK) {
        // ---- stage A tile (128 rows x 32 k) as bf16 ----
        if (A_F32) {
            const float* A = (const float*)Ap;
#pragma unroll
            for (int it = 0; it < 4; ++it) {
                int q   = tid + it * 256;        // quads of 4 floats
                int row = q >> 3;                // 8 quads per 32-float row
                int col = (q & 7) * 4;
                floatx4 f = *reinterpret_cast<const floatx4*>(A + (size_t)(m0 + row) * lda + k0 + col);
                ushortx4 s;
                s.x = f2bf(f.x); s.y = f2bf(f.y); s.z = f2bf(f.z); s.w = f2bf(f.w);
                *reinterpret_cast<ushortx4*>(&As[row * LDT + col]) = s;
            }
        } else {
            const unsigned short* A = (const unsigned short*)Ap;
            int a_row = tid >> 2;                // 0..63
            int a_col = (tid & 3) * 8;           // 0,8,16,24
#pragma unroll
            for (int r = 0; r < 2; ++r) {
                int row = a_row + r * 64;
                uint4 u = *reinterpret_cast<const uint4*>(A + (size_t)(m0 + row) * lda + k0 + a_col);
                *reinterpret_cast<uint4*>(&As[row * LDT + a_col]) = u;
            }
        }
        // ---- stage B tile as Bs[n][k] ----
        if (BT) {
            const unsigned short* Wt = (const unsigned short*)Wp;   // [n][k]
            int b_row = tid >> 2;
            int b_col = (tid & 3) * 8;
#pragma unroll
            for (int r = 0; r < 2; ++r) {
                int n = b_row + r * 64;
                uint4 u = *reinterpret_cast<const uint4*>(Wt + (size_t)(n0 + n) * K + k0 + b_col);
                *reinterpret_cast<uint4*>(&Bs[n * LDT + b_col]) = u;
            }
        } else {
            const float* W = (const float*)Wp;                      // [k][n]
#pragma unroll
            for (int it = 0; it < 4; ++it) {
                int q  = tid + it * 256;
                int kk = q >> 5;
                int nn = (q & 31) * 4;
                floatx4 f = *reinterpret_cast<const floatx4*>(W + (size_t)(k0 + kk) * N + n0 + nn);
                Bs[(nn + 0) * LDT + kk] = f2bf(f.x);
                Bs[(nn + 1) * LDT + kk] = f2bf(f.y);
                Bs[(nn + 2) * LDT + kk] = f2bf(f.z);
                Bs[(nn + 3) * LDT + kk] = f2bf(f.w);
            }
        }
        __syncthreads();

        bf16x8_t av[4], bv[4];
#pragma unroll
        for (int i = 0; i < 4; ++i)
            av[i] = *reinterpret_cast<const bf16x8_t*>(&As[(wm * 64 + i * 16 + lr) * LDT + quad * 8]);
#pragma unroll
        for (int j = 0; j < 4; ++j)
            bv[j] = *reinterpret_cast<const bf16x8_t*>(&Bs[(wn * 64 + j * 16 + lr) * LDT + quad * 8]);

#pragma unroll
        for (int i = 0; i < 4; ++i)
#pragma unroll
            for (int j = 0; j < 4; ++j)
                acc[i][j] = __builtin_amdgcn_mfma_f32_16x16x32_bf16(av[i], bv[j], acc[i][j], 0, 0, 0);

        __syncthreads();
    }

    // epilogue: C/D layout col=lane&15, row=quad*4+reg
#pragma unroll
    for (int j = 0; j < 4; ++j) {
        int col = n0 + wn * 64 + j * 16 + lr;
        float bj = bias[col];
#pragma unroll
        for (int i = 0; i < 4; ++i) {
            int rbase = m0 + wm * 64 + i * 16 + quad * 4;
#pragma unroll
            for (int r = 0; r < 4; ++r) {
                float v = acc[i][j][r] + bj;
                size_t idx = (size_t)(rbase + r) * ldc + col;
                if (C_F32) ((float*)Cp)[idx] = v;
                else       ((unsigned short*)Cp)[idx] = f2bf(v);
            }
        }
    }
}

// ---------------------------------------------------------------------------
// Neighborhood attention 1D: one block per (b,l). K=13, H=16, D=64, L=4096.
// qkv ws (bf16) layout: [(b*L+l)][3*1024], q at +0, k at +1024, v at +2048.
// attn[bl] written IN PLACE into the q-slot: block bl is the only reader of
// q[bl] (staged to LDS first); cross-block reads touch only k/v slots.
// ---------------------------------------------------------------------------
#define NA_L 4096
#define NA_K 13
#define NA_H 16
#define NA_D 64
#define NA_SCALE 0.125f

__global__ __launch_bounds__(256) void na1d_kernel(
    unsigned short* qkv, const float* __restrict__ rpb)
{
    __shared__ float qs[NA_H * NA_D];      // 1024 scaled q
    __shared__ float wgt[NA_H][NA_K];      // logits -> weights

    const int bl = blockIdx.x;             // b*4096 + l
    const int b  = bl >> 12;
    const int l  = bl & 4095;
    int ni = l - 6;
    if (ni < 0) ni = 0;
    if (ni > NA_L - NA_K) ni = NA_L - NA_K;

    const int t = threadIdx.x;
    unsigned short* qrow = qkv + (size_t)bl * 3072;

    // load + scale q (4 elems/thread)
    {
        uint2 raw = *reinterpret_cast<const uint2*>(qrow + t * 4);
        qs[t * 4 + 0] = bf2f((unsigned short)(raw.x & 0xffff)) * NA_SCALE;
        qs[t * 4 + 1] = bf2f((unsigned short)(raw.x >> 16)) * NA_SCALE;
        qs[t * 4 + 2] = bf2f((unsigned short)(raw.y & 0xffff)) * NA_SCALE;
        qs[t * 4 + 3] = bf2f((unsigned short)(raw.y >> 16)) * NA_SCALE;
    }
    __syncthreads();

    // logits: 16 heads x 13 neighbors
    if (t < NA_H * NA_K) {
        int h = t / NA_K;
        int j = t - h * NA_K;
        const unsigned short* krow = qkv + (size_t)(b * NA_L + ni + j) * 3072 + 1024 + h * 64;
        const float* qh = &qs[h * 64];
        float s = 0.f;
#pragma unroll
        for (int d = 0; d < NA_D; d += 8) {
            uint4 kr = *reinterpret_cast<const uint4*>(krow + d);
            s += qh[d + 0] * bf2f((unsigned short)(kr.x & 0xffff));
            s += qh[d + 1] * bf2f((unsigned short)(kr.x >> 16));
            s += qh[d + 2] * bf2f((unsigned short)(kr.y & 0xffff));
            s += qh[d + 3] * bf2f((unsigned short)(kr.y >> 16));
            s += qh[d + 4] * bf2f((unsigned short)(kr.z & 0xffff));
            s += qh[d + 5] * bf2f((unsigned short)(kr.z >> 16));
            s += qh[d + 6] * bf2f((unsigned short)(kr.w & 0xffff));
            s += qh[d + 7] * bf2f((unsigned short)(kr.w >> 16));
        }
        int pi = ni - l + 12;
        s += rpb[h * 25 + pi + j];
        wgt[h][j] = s;
    }
    __syncthreads();

    // softmax per head
    if (t < NA_H) {
        float m = -1e30f;
#pragma unroll
        for (int j = 0; j < NA_K; ++j) m = fmaxf(m, wgt[t][j]);
        float sum = 0.f;
#pragma unroll
        for (int j = 0; j < NA_K; ++j) {
            float e = expf(wgt[t][j] - m);
            wgt[t][j] = e;
            sum += e;
        }
        float inv = 1.f / sum;
#pragma unroll
        for (int j = 0; j < NA_K; ++j) wgt[t][j] *= inv;
    }
    __syncthreads();

    // output: each thread does 4 dims of one head; write into own q-slot
    const int h  = t >> 4;
    const int d0 = (t & 15) * 4;
    float o0 = 0.f, o1 = 0.f, o2 = 0.f, o3 = 0.f;
#pragma unroll
    for (int j = 0; j < NA_K; ++j) {
        float w = wgt[h][j];
        const unsigned short* vrow = qkv + (size_t)(b * NA_L + ni + j) * 3072 + 2048 + h * 64 + d0;
        uint2 vr = *reinterpret_cast<const uint2*>(vrow);
        o0 += w * bf2f((unsigned short)(vr.x & 0xffff));
        o1 += w * bf2f((unsigned short)(vr.x >> 16));
        o2 += w * bf2f((unsigned short)(vr.y & 0xffff));
        o3 += w * bf2f((unsigned short)(vr.y >> 16));
    }
    uint2 packed;
    packed.x = (unsigned int)f2bf(o0) | ((unsigned int)f2bf(o1) << 16);
    packed.y = (unsigned int)f2bf(o2) | ((unsigned int)f2bf(o3) << 16);
    *reinterpret_cast<uint2*>(qrow + h * 64 + d0) = packed;
}

// ---------------------------------------------------------------------------
extern "C" void kernel_launch(void* const* d_in, const int* in_sizes, int n_in,
                              void* d_out, int out_size, void* d_ws, size_t ws_size,
                              hipStream_t stream)
{
    const float* x      = (const float*)d_in[0]; // (4,4096,1024) f32
    const float* w_qkv  = (const float*)d_in[1]; // (1024,3072)   f32
    const float* b_qkv  = (const float*)d_in[2]; // (3072,)       f32
    const float* rpb    = (const float*)d_in[3]; // (16,25)       f32
    const float* w_proj = (const float*)d_in[4]; // (1024,1024)   f32
    const float* b_proj = (const float*)d_in[5]; // (1024,)       f32
    float* out = (float*)d_out;                  // (4,4096,1024) f32

    const int M  = 4 * 4096;   // 16384
    const int K  = 1024;
    const int N1 = 3072;
    const int N2 = 1024;

    unsigned short* qkv = (unsigned short*)d_ws;              // M*N1 bf16 = 96 MiB
    unsigned short* Wt1 = qkv + (size_t)M * N1;               // 6 MiB
    unsigned short* Wt2 = Wt1 + (size_t)N1 * K;               // 2 MiB
    size_t need = ((size_t)M * N1 + (size_t)N1 * K + (size_t)N2 * K) * sizeof(unsigned short);

    if (ws_size >= need) {
        // fast path: pre-transpose weights to bf16 [n][k]
        transpose_f32_to_bf16<<<dim3(N1 / 32, K / 32), 256, 0, stream>>>(w_qkv, Wt1, K, N1);
        transpose_f32_to_bf16<<<dim3(N2 / 32, K / 32), 256, 0, stream>>>(w_proj, Wt2, K, N2);
        gemm_bias_kernel<true, false, true><<<dim3(N1 / BN, M / BM), 256, 0, stream>>>(
            x, Wt1, b_qkv, qkv, N1, K, K, N1);
        na1d_kernel<<<dim3(M), 256, 0, stream>>>(qkv, rpb);
        gemm_bias_kernel<false, true, true><<<dim3(N2 / BN, M / BM), 256, 0, stream>>>(
            qkv, Wt2, b_proj, out, N2, K, N1, N2);
    } else {
        // fallback: round-3 proven path (scatter B staging)
        gemm_bias_kernel<true, false, false><<<dim3(N1 / BN, M / BM), 256, 0, stream>>>(
            x, w_qkv, b_qkv, qkv, N1, K, K, N1);
        na1d_kernel<<<dim3(M), 256, 0, stream>>>(qkv, rpb);
        gemm_bias_kernel<false, true, false><<<dim3(N2 / BN, M / BM), 256, 0, stream>>>(
            qkv, w_proj, b_proj, out, N2, K, N1, N2);
    }
}

// Round 5
// 446.073 us; speedup vs baseline: 1.8136x; 1.0623x over previous
//
#include <hip/hip_runtime.h>

typedef __bf16 bf16x8_t __attribute__((ext_vector_type(8)));
typedef float  f32x4_t  __attribute__((ext_vector_type(4)));
typedef float  floatx4  __attribute__((ext_vector_type(4)));
typedef unsigned short ushortx4 __attribute__((ext_vector_type(4)));

__device__ __forceinline__ float bf2f(unsigned short u) {
    union { unsigned int i; float f; } c; c.i = ((unsigned int)u) << 16; return c.f;
}
__device__ __forceinline__ unsigned short f2bf(float f) {
    union { float f; unsigned int i; } c; c.f = f;
    unsigned int u = c.i;
    u += 0x7fffu + ((u >> 16) & 1u);   // RNE
    return (unsigned short)(u >> 16);
}

// async global->LDS, 16 B per lane; lds dest = wave-uniform base + lane*16
__device__ __forceinline__ void load_lds16(const unsigned short* g, unsigned short* l) {
    __builtin_amdgcn_global_load_lds(
        (const __attribute__((address_space(1))) unsigned int*)g,
        (__attribute__((address_space(3))) unsigned int*)l, 16, 0, 0);
}

// ---------------------------------------------------------------------------
// x (f32) -> bf16, 8 elems/thread
// ---------------------------------------------------------------------------
__global__ __launch_bounds__(256) void convert_f32_bf16(
    const float* __restrict__ x, unsigned short* __restrict__ xb)
{
    size_t i = ((size_t)blockIdx.x * 256 + threadIdx.x) * 8;
    floatx4 a = *reinterpret_cast<const floatx4*>(x + i);
    floatx4 b = *reinterpret_cast<const floatx4*>(x + i + 4);
    uint4 o;
    o.x = (unsigned int)f2bf(a.x) | ((unsigned int)f2bf(a.y) << 16);
    o.y = (unsigned int)f2bf(a.z) | ((unsigned int)f2bf(a.w) << 16);
    o.z = (unsigned int)f2bf(b.x) | ((unsigned int)f2bf(b.y) << 16);
    o.w = (unsigned int)f2bf(b.z) | ((unsigned int)f2bf(b.w) << 16);
    *reinterpret_cast<uint4*>(xb + i) = o;
}

// ---------------------------------------------------------------------------
// Weight prep: Wt[n][k] (bf16) = W[k][n] (f32). 32x32 LDS-tiled transpose.
// ---------------------------------------------------------------------------
__global__ __launch_bounds__(256) void transpose_f32_to_bf16(
    const float* __restrict__ W, unsigned short* __restrict__ Wt,
    int Kdim, int Ndim)
{
    __shared__ float tile[32][33];
    const int n0 = blockIdx.x * 32, k0 = blockIdx.y * 32;
    const int tx = threadIdx.x & 31, ty = threadIdx.x >> 5;   // ty 0..7
#pragma unroll
    for (int r = 0; r < 4; ++r) {
        int k = ty + r * 8;
        tile[k][tx] = W[(size_t)(k0 + k) * Ndim + n0 + tx];
    }
    __syncthreads();
#pragma unroll
    for (int r = 0; r < 4; ++r) {
        int n = ty + r * 8;
        Wt[(size_t)(n0 + n) * Kdim + k0 + tx] = f2bf(tile[tx][n]);
    }
}

// ---------------------------------------------------------------------------
// m97-style GEMM: C(MxN) = A(MxK) @ Wt(N x K, pre-transposed) + bias, all-bf16
// inputs, fp32 acc, 16x16x32 MFMA. 128x128 tile, BK=32, 4 waves x (4x4).
// Staging via global_load_lds dwordx4 into UNPADDED [128][32] LDS (8 KB each);
// wave-uniform dest: lane l of wave w lands at base + w*1024 + l*16 B, which
// equals row (w*16 + (l>>2)), col (l&3)*8 of the tile. No VGPR round-trip,
// no LDS-write conflicts (HW DMA).
// ---------------------------------------------------------------------------
#define BM 128
#define BN 128
#define BK 32

template<bool C_F32>
__global__ __launch_bounds__(256) void gemm_lds_kernel(
    const unsigned short* __restrict__ A, const unsigned short* __restrict__ Wt,
    const float* __restrict__ bias, void* __restrict__ Cp,
    int N, int K, int lda, int ldc)
{
    __shared__ __align__(16) unsigned short As[BM * BK];
    __shared__ __align__(16) unsigned short Bs[BN * BK];

    const int tid  = threadIdx.x;
    const int lane = tid & 63;
    const int wid  = tid >> 6;       // 0..3
    const int wm   = wid >> 1;       // 0..1
    const int wn   = wid & 1;        // 0..1
    const int quad = lane >> 4;      // 0..3
    const int lr   = lane & 15;      // 0..15

    const int m0 = blockIdx.y * BM;
    const int n0 = blockIdx.x * BN;

    const int s_row = tid >> 2;            // 0..63
    const int s_col = (tid & 3) * 8;       // shorts
    unsigned short* ldsA = As + wid * 512; // 1024 B per wave
    unsigned short* ldsB = Bs + wid * 512;

    f32x4_t acc[4][4];
#pragma unroll
    for (int i = 0; i < 4; ++i)
#pragma unroll
        for (int j = 0; j < 4; ++j)
            acc[i][j] = (f32x4_t){0.f, 0.f, 0.f, 0.f};

    for (int k0 = 0; k0 < K; k0 += BK) {
#pragma unroll
        for (int r = 0; r < 2; ++r) {
            load_lds16(A  + (size_t)(m0 + s_row + r * 64) * lda + k0 + s_col, ldsA + r * 2048);
            load_lds16(Wt + (size_t)(n0 + s_row + r * 64) * K   + k0 + s_col, ldsB + r * 2048);
        }
        __syncthreads();   // drains vmcnt(0): global_load_lds complete

        bf16x8_t av[4], bv[4];
#pragma unroll
        for (int i = 0; i < 4; ++i)
            av[i] = *reinterpret_cast<const bf16x8_t*>(&As[(wm * 64 + i * 16 + lr) * BK + quad * 8]);
#pragma unroll
        for (int j = 0; j < 4; ++j)
            bv[j] = *reinterpret_cast<const bf16x8_t*>(&Bs[(wn * 64 + j * 16 + lr) * BK + quad * 8]);

#pragma unroll
        for (int i = 0; i < 4; ++i)
#pragma unroll
            for (int j = 0; j < 4; ++j)
                acc[i][j] = __builtin_amdgcn_mfma_f32_16x16x32_bf16(av[i], bv[j], acc[i][j], 0, 0, 0);

        __syncthreads();
    }

    // epilogue: C/D layout col=lane&15, row=quad*4+reg
#pragma unroll
    for (int j = 0; j < 4; ++j) {
        int col = n0 + wn * 64 + j * 16 + lr;
        float bj = bias[col];
#pragma unroll
        for (int i = 0; i < 4; ++i) {
            int rbase = m0 + wm * 64 + i * 16 + quad * 4;
#pragma unroll
            for (int r = 0; r < 4; ++r) {
                float v = acc[i][j][r] + bj;
                size_t idx = (size_t)(rbase + r) * ldc + col;
                if (C_F32) ((float*)Cp)[idx] = v;
                else       ((unsigned short*)Cp)[idx] = f2bf(v);
            }
        }
    }
}

// ---------------------------------------------------------------------------
// Fallback GEMM (R3/R4-proven): padded LDS, regular staging.
// ---------------------------------------------------------------------------
#define LDT 40

template<bool A_F32, bool C_F32, bool BT>
__global__ __launch_bounds__(256) void gemm_bias_kernel(
    const void* __restrict__ Ap, const void* __restrict__ Wp,
    const float* __restrict__ bias, void* __restrict__ Cp,
    int N, int K, int lda, int ldc)
{
    __shared__ __align__(16) unsigned short As[BM * LDT];
    __shared__ __align__(16) unsigned short Bs[BN * LDT];

    const int tid  = threadIdx.x;
    const int lane = tid & 63;
    const int wid  = tid >> 6;
    const int wm   = wid >> 1;
    const int wn   = wid & 1;
    const int quad = lane >> 4;
    const int lr   = lane & 15;

    const int m0 = blockIdx.y * BM;
    const int n0 = blockIdx.x * BN;

    f32x4_t acc[4][4];
#pragma unroll
    for (int i = 0; i < 4; ++i)
#pragma unroll
        for (int j = 0; j < 4; ++j)
            acc[i][j] = (f32x4_t){0.f, 0.f, 0.f, 0.f};

    for (int k0 = 0; k0 < K; k0 += BK) {
        if (A_F32) {
            const float* A = (const float*)Ap;
#pragma unroll
            for (int it = 0; it < 4; ++it) {
                int q   = tid + it * 256;
                int row = q >> 3;
                int col = (q & 7) * 4;
                floatx4 f = *reinterpret_cast<const floatx4*>(A + (size_t)(m0 + row) * lda + k0 + col);
                ushortx4 s;
                s.x = f2bf(f.x); s.y = f2bf(f.y); s.z = f2bf(f.z); s.w = f2bf(f.w);
                *reinterpret_cast<ushortx4*>(&As[row * LDT + col]) = s;
            }
        } else {
            const unsigned short* A = (const unsigned short*)Ap;
            int a_row = tid >> 2;
            int a_col = (tid & 3) * 8;
#pragma unroll
            for (int r = 0; r < 2; ++r) {
                int row = a_row + r * 64;
                uint4 u = *reinterpret_cast<const uint4*>(A + (size_t)(m0 + row) * lda + k0 + a_col);
                *reinterpret_cast<uint4*>(&As[row * LDT + a_col]) = u;
            }
        }
        if (BT) {
            const unsigned short* Wt = (const unsigned short*)Wp;
            int b_row = tid >> 2;
            int b_col = (tid & 3) * 8;
#pragma unroll
            for (int r = 0; r < 2; ++r) {
                int n = b_row + r * 64;
                uint4 u = *reinterpret_cast<const uint4*>(Wt + (size_t)(n0 + n) * K + k0 + b_col);
                *reinterpret_cast<uint4*>(&Bs[n * LDT + b_col]) = u;
            }
        } else {
            const float* W = (const float*)Wp;
#pragma unroll
            for (int it = 0; it < 4; ++it) {
                int q  = tid + it * 256;
                int kk = q >> 5;
                int nn = (q & 31) * 4;
                floatx4 f = *reinterpret_cast<const floatx4*>(W + (size_t)(k0 + kk) * N + n0 + nn);
                Bs[(nn + 0) * LDT + kk] = f2bf(f.x);
                Bs[(nn + 1) * LDT + kk] = f2bf(f.y);
                Bs[(nn + 2) * LDT + kk] = f2bf(f.z);
                Bs[(nn + 3) * LDT + kk] = f2bf(f.w);
            }
        }
        __syncthreads();

        bf16x8_t av[4], bv[4];
#pragma unroll
        for (int i = 0; i < 4; ++i)
            av[i] = *reinterpret_cast<const bf16x8_t*>(&As[(wm * 64 + i * 16 + lr) * LDT + quad * 8]);
#pragma unroll
        for (int j = 0; j < 4; ++j)
            bv[j] = *reinterpret_cast<const bf16x8_t*>(&Bs[(wn * 64 + j * 16 + lr) * LDT + quad * 8]);

#pragma unroll
        for (int i = 0; i < 4; ++i)
#pragma unroll
            for (int j = 0; j < 4; ++j)
                acc[i][j] = __builtin_amdgcn_mfma_f32_16x16x32_bf16(av[i], bv[j], acc[i][j], 0, 0, 0);

        __syncthreads();
    }

#pragma unroll
    for (int j = 0; j < 4; ++j) {
        int col = n0 + wn * 64 + j * 16 + lr;
        float bj = bias[col];
#pragma unroll
        for (int i = 0; i < 4; ++i) {
            int rbase = m0 + wm * 64 + i * 16 + quad * 4;
#pragma unroll
            for (int r = 0; r < 4; ++r) {
                float v = acc[i][j][r] + bj;
                size_t idx = (size_t)(rbase + r) * ldc + col;
                if (C_F32) ((float*)Cp)[idx] = v;
                else       ((unsigned short*)Cp)[idx] = f2bf(v);
            }
        }
    }
}

// ---------------------------------------------------------------------------
// Neighborhood attention 1D: one block per (b,l). K=13, H=16, D=64, L=4096.
// qkv ws (bf16) layout: [(b*L+l)][3*1024], q at +0, k at +1024, v at +2048.
// attn[bl] written IN PLACE into the q-slot (block bl is q[bl]'s only reader).
// blockIdx -> bl swizzled so each XCD (dispatch round-robin i%8) walks a
// CONTIGUOUS 2048-wide l-range: active kv window ~1.2 MB << 4 MiB L2/XCD.
// Speed heuristic only — any XCD mapping is still correct.
// ---------------------------------------------------------------------------
#define NA_L 4096
#define NA_K 13
#define NA_H 16
#define NA_D 64
#define NA_SCALE 0.125f

__global__ __launch_bounds__(256) void na1d_kernel(
    unsigned short* qkv, const float* __restrict__ rpb)
{
    __shared__ float qs[NA_H * NA_D];
    __shared__ float wgt[NA_H][NA_K];

    const int i  = blockIdx.x;
    const int bl = ((i & 7) << 11) | (i >> 3);   // XCD-contiguous swizzle
    const int b  = bl >> 12;
    const int l  = bl & 4095;
    int ni = l - 6;
    if (ni < 0) ni = 0;
    if (ni > NA_L - NA_K) ni = NA_L - NA_K;

    const int t = threadIdx.x;
    unsigned short* qrow = qkv + (size_t)bl * 3072;

    {
        uint2 raw = *reinterpret_cast<const uint2*>(qrow + t * 4);
        qs[t * 4 + 0] = bf2f((unsigned short)(raw.x & 0xffff)) * NA_SCALE;
        qs[t * 4 + 1] = bf2f((unsigned short)(raw.x >> 16)) * NA_SCALE;
        qs[t * 4 + 2] = bf2f((unsigned short)(raw.y & 0xffff)) * NA_SCALE;
        qs[t * 4 + 3] = bf2f((unsigned short)(raw.y >> 16)) * NA_SCALE;
    }
    __syncthreads();

    if (t < NA_H * NA_K) {
        int h = t / NA_K;
        int j = t - h * NA_K;
        const unsigned short* krow = qkv + (size_t)(b * NA_L + ni + j) * 3072 + 1024 + h * 64;
        const float* qh = &qs[h * 64];
        float s = 0.f;
#pragma unroll
        for (int d = 0; d < NA_D; d += 8) {
            uint4 kr = *reinterpret_cast<const uint4*>(krow + d);
            s += qh[d + 0] * bf2f((unsigned short)(kr.x & 0xffff));
            s += qh[d + 1] * bf2f((unsigned short)(kr.x >> 16));
            s += qh[d + 2] * bf2f((unsigned short)(kr.y & 0xffff));
            s += qh[d + 3] * bf2f((unsigned short)(kr.y >> 16));
            s += qh[d + 4] * bf2f((unsigned short)(kr.z & 0xffff));
            s += qh[d + 5] * bf2f((unsigned short)(kr.z >> 16));
            s += qh[d + 6] * bf2f((unsigned short)(kr.w & 0xffff));
            s += qh[d + 7] * bf2f((unsigned short)(kr.w >> 16));
        }
        int pi = ni - l + 12;
        s += rpb[h * 25 + pi + j];
        wgt[h][j] = s;
    }
    __syncthreads();

    if (t < NA_H) {
        float m = -1e30f;
#pragma unroll
        for (int j = 0; j < NA_K; ++j) m = fmaxf(m, wgt[t][j]);
        float sum = 0.f;
#pragma unroll
        for (int j = 0; j < NA_K; ++j) {
            float e = expf(wgt[t][j] - m);
            wgt[t][j] = e;
            sum += e;
        }
        float inv = 1.f / sum;
#pragma unroll
        for (int j = 0; j < NA_K; ++j) wgt[t][j] *= inv;
    }
    __syncthreads();

    const int h  = t >> 4;
    const int d0 = (t & 15) * 4;
    float o0 = 0.f, o1 = 0.f, o2 = 0.f, o3 = 0.f;
#pragma unroll
    for (int j = 0; j < NA_K; ++j) {
        float w = wgt[h][j];
        const unsigned short* vrow = qkv + (size_t)(b * NA_L + ni + j) * 3072 + 2048 + h * 64 + d0;
        uint2 vr = *reinterpret_cast<const uint2*>(vrow);
        o0 += w * bf2f((unsigned short)(vr.x & 0xffff));
        o1 += w * bf2f((unsigned short)(vr.x >> 16));
        o2 += w * bf2f((unsigned short)(vr.y & 0xffff));
        o3 += w * bf2f((unsigned short)(vr.y >> 16));
    }
    uint2 packed;
    packed.x = (unsigned int)f2bf(o0) | ((unsigned int)f2bf(o1) << 16);
    packed.y = (unsigned int)f2bf(o2) | ((unsigned int)f2bf(o3) << 16);
    *reinterpret_cast<uint2*>(qrow + h * 64 + d0) = packed;
}

// ---------------------------------------------------------------------------
extern "C" void kernel_launch(void* const* d_in, const int* in_sizes, int n_in,
                              void* d_out, int out_size, void* d_ws, size_t ws_size,
                              hipStream_t stream)
{
    const float* x      = (const float*)d_in[0];
    const float* w_qkv  = (const float*)d_in[1];
    const float* b_qkv  = (const float*)d_in[2];
    const float* rpb    = (const float*)d_in[3];
    const float* w_proj = (const float*)d_in[4];
    const float* b_proj = (const float*)d_in[5];
    float* out = (float*)d_out;

    const int M  = 4 * 4096;   // 16384
    const int K  = 1024;
    const int N1 = 3072;
    const int N2 = 1024;

    unsigned short* qkv = (unsigned short*)d_ws;              // 96 MiB
    unsigned short* Wt1 = qkv + (size_t)M * N1;               // 6 MiB
    unsigned short* Wt2 = Wt1 + (size_t)N1 * K;               // 2 MiB
    unsigned short* xb  = Wt2 + (size_t)N2 * K;               // 32 MiB
    size_t need_mid  = ((size_t)M * N1 + (size_t)N1 * K + (size_t)N2 * K) * 2;
    size_t need_fast = need_mid + (size_t)M * K * 2;

    if (ws_size >= need_fast) {
        // fast: all-bf16 operands + global_load_lds staging (m97 structure)
        convert_f32_bf16<<<dim3(M * K / (256 * 8)), 256, 0, stream>>>(x, xb);
        transpose_f32_to_bf16<<<dim3(N1 / 32, K / 32), 256, 0, stream>>>(w_qkv, Wt1, K, N1);
        transpose_f32_to_bf16<<<dim3(N2 / 32, K / 32), 256, 0, stream>>>(w_proj, Wt2, K, N2);
        gemm_lds_kernel<false><<<dim3(N1 / BN, M / BM), 256, 0, stream>>>(
            xb, Wt1, b_qkv, qkv, N1, K, K, N1);
        na1d_kernel<<<dim3(M), 256, 0, stream>>>(qkv, rpb);
        gemm_lds_kernel<true><<<dim3(N2 / BN, M / BM), 256, 0, stream>>>(
            qkv, Wt2, b_proj, out, N2, K, N1, N2);
    } else if (ws_size >= need_mid) {
        // mid (R4-proven): pre-transposed weights, padded-LDS staging
        transpose_f32_to_bf16<<<dim3(N1 / 32, K / 32), 256, 0, stream>>>(w_qkv, Wt1, K, N1);
        transpose_f32_to_bf16<<<dim3(N2 / 32, K / 32), 256, 0, stream>>>(w_proj, Wt2, K, N2);
        gemm_bias_kernel<true, false, true><<<dim3(N1 / BN, M / BM), 256, 0, stream>>>(
            x, Wt1, b_qkv, qkv, N1, K, K, N1);
        na1d_kernel<<<dim3(M), 256, 0, stream>>>(qkv, rpb);
        gemm_bias_kernel<false, true, true><<<dim3(N2 / BN, M / BM), 256, 0, stream>>>(
            qkv, Wt2, b_proj, out, N2, K, N1, N2);
    } else {
        // basic (R3-proven)
        gemm_bias_kernel<true, false, false><<<dim3(N1 / BN, M / BM), 256, 0, stream>>>(
            x, w_qkv, b_qkv, qkv, N1, K, K, N1);
        na1d_kernel<<<dim3(M), 256, 0, stream>>>(qkv, rpb);
        gemm_bias_kernel<false, true, false><<<dim3(N2 / BN, M / BM), 256, 0, stream>>>(
            qkv, w_proj, b_proj, out, N2, K, N1, N2);
    }
}

// Round 6
// 437.503 us; speedup vs baseline: 1.8491x; 1.0196x over previous
//
#include <hip/hip_runtime.h>

typedef __bf16 bf16x8_t __attribute__((ext_vector_type(8)));
typedef float  f32x4_t  __attribute__((ext_vector_type(4)));
typedef float  floatx4  __attribute__((ext_vector_type(4)));
typedef unsigned short ushortx4 __attribute__((ext_vector_type(4)));

__device__ __forceinline__ float bf2f(unsigned short u) {
    union { unsigned int i; float f; } c; c.i = ((unsigned int)u) << 16; return c.f;
}
__device__ __forceinline__ unsigned short f2bf(float f) {
    union { float f; unsigned int i; } c; c.f = f;
    unsigned int u = c.i;
    u += 0x7fffu + ((u >> 16) & 1u);   // RNE
    return (unsigned short)(u >> 16);
}
__device__ __forceinline__ void unpack8(uint4 u, float* dst, float sc) {
    dst[0] = bf2f((unsigned short)(u.x & 0xffff)) * sc;
    dst[1] = bf2f((unsigned short)(u.x >> 16)) * sc;
    dst[2] = bf2f((unsigned short)(u.y & 0xffff)) * sc;
    dst[3] = bf2f((unsigned short)(u.y >> 16)) * sc;
    dst[4] = bf2f((unsigned short)(u.z & 0xffff)) * sc;
    dst[5] = bf2f((unsigned short)(u.z >> 16)) * sc;
    dst[6] = bf2f((unsigned short)(u.w & 0xffff)) * sc;
    dst[7] = bf2f((unsigned short)(u.w >> 16)) * sc;
}

// async global->LDS, 16 B per lane; lds dest = wave-uniform base + lane*16
__device__ __forceinline__ void load_lds16(const unsigned short* g, unsigned short* l) {
    __builtin_amdgcn_global_load_lds(
        (const __attribute__((address_space(1))) unsigned int*)g,
        (__attribute__((address_space(3))) unsigned int*)l, 16, 0, 0);
}

// ---------------------------------------------------------------------------
// x (f32) -> bf16, 8 elems/thread
// ---------------------------------------------------------------------------
__global__ __launch_bounds__(256) void convert_f32_bf16(
    const float* __restrict__ x, unsigned short* __restrict__ xb)
{
    size_t i = ((size_t)blockIdx.x * 256 + threadIdx.x) * 8;
    floatx4 a = *reinterpret_cast<const floatx4*>(x + i);
    floatx4 b = *reinterpret_cast<const floatx4*>(x + i + 4);
    uint4 o;
    o.x = (unsigned int)f2bf(a.x) | ((unsigned int)f2bf(a.y) << 16);
    o.y = (unsigned int)f2bf(a.z) | ((unsigned int)f2bf(a.w) << 16);
    o.z = (unsigned int)f2bf(b.x) | ((unsigned int)f2bf(b.y) << 16);
    o.w = (unsigned int)f2bf(b.z) | ((unsigned int)f2bf(b.w) << 16);
    *reinterpret_cast<uint4*>(xb + i) = o;
}

// ---------------------------------------------------------------------------
// Weight prep: Wt[n][k] (bf16) = W[k][n] (f32). 32x32 LDS-tiled transpose.
// ---------------------------------------------------------------------------
__global__ __launch_bounds__(256) void transpose_f32_to_bf16(
    const float* __restrict__ W, unsigned short* __restrict__ Wt,
    int Kdim, int Ndim)
{
    __shared__ float tile[32][33];
    const int n0 = blockIdx.x * 32, k0 = blockIdx.y * 32;
    const int tx = threadIdx.x & 31, ty = threadIdx.x >> 5;   // ty 0..7
#pragma unroll
    for (int r = 0; r < 4; ++r) {
        int k = ty + r * 8;
        tile[k][tx] = W[(size_t)(k0 + k) * Ndim + n0 + tx];
    }
    __syncthreads();
#pragma unroll
    for (int r = 0; r < 4; ++r) {
        int n = ty + r * 8;
        Wt[(size_t)(n0 + n) * Kdim + k0 + tx] = f2bf(tile[tx][n]);
    }
}

// ---------------------------------------------------------------------------
// m97-style GEMM with XOR-swizzled LDS. C = A(MxK,bf16) @ Wt(NxK,bf16) + bias.
// Layout: chunk c (16B) of tile row r stored at chunk position c ^ ((r>>1)&3).
// global_load_lds dest is wave-uniform+lane*16, so the swizzle is applied on
// the SOURCE address (lane l fetches chunk (l&3)^((l>>3)&3)); fragment reads
// use position quad ^ ((lr>>1)&3). Both lane-constant. Result: each 8-lane
// group of a ds_read_b128 covers all 8 4-bank positions -> conflict-free.
// ---------------------------------------------------------------------------
#define BM 128
#define BN 128
#define BK 32

template<bool C_F32>
__global__ __launch_bounds__(256) void gemm_lds_kernel(
    const unsigned short* __restrict__ A, const unsigned short* __restrict__ Wt,
    const float* __restrict__ bias, void* __restrict__ Cp,
    int N, int K, int lda, int ldc)
{
    __shared__ __align__(16) unsigned short As[BM * BK];
    __shared__ __align__(16) unsigned short Bs[BN * BK];

    const int tid  = threadIdx.x;
    const int lane = tid & 63;
    const int wid  = tid >> 6;       // 0..3
    const int wm   = wid >> 1;       // 0..1
    const int wn   = wid & 1;        // 0..1
    const int quad = lane >> 4;      // 0..3
    const int lr   = lane & 15;      // 0..15

    const int m0 = blockIdx.y * BM;
    const int n0 = blockIdx.x * BN;

    const int s_row = tid >> 2;                                  // 0..63
    const int c_sw  = ((tid & 3) ^ ((tid >> 3) & 3)) * 8;        // swizzled source chunk (shorts)
    const int xq    = (quad ^ ((lr >> 1) & 3)) * 8;              // swizzled read chunk (shorts)
    unsigned short* ldsA = As + wid * 512;                       // 1024 B per wave
    unsigned short* ldsB = Bs + wid * 512;

    f32x4_t acc[4][4];
#pragma unroll
    for (int i = 0; i < 4; ++i)
#pragma unroll
        for (int j = 0; j < 4; ++j)
            acc[i][j] = (f32x4_t){0.f, 0.f, 0.f, 0.f};

    for (int k0 = 0; k0 < K; k0 += BK) {
#pragma unroll
        for (int r = 0; r < 2; ++r) {
            load_lds16(A  + (size_t)(m0 + s_row + r * 64) * lda + k0 + c_sw, ldsA + r * 2048);
            load_lds16(Wt + (size_t)(n0 + s_row + r * 64) * K   + k0 + c_sw, ldsB + r * 2048);
        }
        __syncthreads();

        bf16x8_t av[4], bv[4];
#pragma unroll
        for (int i = 0; i < 4; ++i)
            av[i] = *reinterpret_cast<const bf16x8_t*>(&As[(wm * 64 + i * 16 + lr) * BK + xq]);
#pragma unroll
        for (int j = 0; j < 4; ++j)
            bv[j] = *reinterpret_cast<const bf16x8_t*>(&Bs[(wn * 64 + j * 16 + lr) * BK + xq]);

#pragma unroll
        for (int i = 0; i < 4; ++i)
#pragma unroll
            for (int j = 0; j < 4; ++j)
                acc[i][j] = __builtin_amdgcn_mfma_f32_16x16x32_bf16(av[i], bv[j], acc[i][j], 0, 0, 0);

        __syncthreads();
    }

    // epilogue: C/D layout col=lane&15, row=quad*4+reg
#pragma unroll
    for (int j = 0; j < 4; ++j) {
        int col = n0 + wn * 64 + j * 16 + lr;
        float bj = bias[col];
#pragma unroll
        for (int i = 0; i < 4; ++i) {
            int rbase = m0 + wm * 64 + i * 16 + quad * 4;
#pragma unroll
            for (int r = 0; r < 4; ++r) {
                float v = acc[i][j][r] + bj;
                size_t idx = (size_t)(rbase + r) * ldc + col;
                if (C_F32) ((float*)Cp)[idx] = v;
                else       ((unsigned short*)Cp)[idx] = f2bf(v);
            }
        }
    }
}

// ---------------------------------------------------------------------------
// Fallback GEMM (R3/R4-proven): padded LDS, regular staging.
// ---------------------------------------------------------------------------
#define LDT 40

template<bool A_F32, bool C_F32, bool BT>
__global__ __launch_bounds__(256) void gemm_bias_kernel(
    const void* __restrict__ Ap, const void* __restrict__ Wp,
    const float* __restrict__ bias, void* __restrict__ Cp,
    int N, int K, int lda, int ldc)
{
    __shared__ __align__(16) unsigned short As[BM * LDT];
    __shared__ __align__(16) unsigned short Bs[BN * LDT];

    const int tid  = threadIdx.x;
    const int lane = tid & 63;
    const int wid  = tid >> 6;
    const int wm   = wid >> 1;
    const int wn   = wid & 1;
    const int quad = lane >> 4;
    const int lr   = lane & 15;

    const int m0 = blockIdx.y * BM;
    const int n0 = blockIdx.x * BN;

    f32x4_t acc[4][4];
#pragma unroll
    for (int i = 0; i < 4; ++i)
#pragma unroll
        for (int j = 0; j < 4; ++j)
            acc[i][j] = (f32x4_t){0.f, 0.f, 0.f, 0.f};

    for (int k0 = 0; k0 < K; k0 += BK) {
        if (A_F32) {
            const float* A = (const float*)Ap;
#pragma unroll
            for (int it = 0; it < 4; ++it) {
                int q   = tid + it * 256;
                int row = q >> 3;
                int col = (q & 7) * 4;
                floatx4 f = *reinterpret_cast<const floatx4*>(A + (size_t)(m0 + row) * lda + k0 + col);
                ushortx4 s;
                s.x = f2bf(f.x); s.y = f2bf(f.y); s.z = f2bf(f.z); s.w = f2bf(f.w);
                *reinterpret_cast<ushortx4*>(&As[row * LDT + col]) = s;
            }
        } else {
            const unsigned short* A = (const unsigned short*)Ap;
            int a_row = tid >> 2;
            int a_col = (tid & 3) * 8;
#pragma unroll
            for (int r = 0; r < 2; ++r) {
                int row = a_row + r * 64;
                uint4 u = *reinterpret_cast<const uint4*>(A + (size_t)(m0 + row) * lda + k0 + a_col);
                *reinterpret_cast<uint4*>(&As[row * LDT + a_col]) = u;
            }
        }
        if (BT) {
            const unsigned short* Wt = (const unsigned short*)Wp;
            int b_row = tid >> 2;
            int b_col = (tid & 3) * 8;
#pragma unroll
            for (int r = 0; r < 2; ++r) {
                int n = b_row + r * 64;
                uint4 u = *reinterpret_cast<const uint4*>(Wt + (size_t)(n0 + n) * K + k0 + b_col);
                *reinterpret_cast<uint4*>(&Bs[n * LDT + b_col]) = u;
            }
        } else {
            const float* W = (const float*)Wp;
#pragma unroll
            for (int it = 0; it < 4; ++it) {
                int q  = tid + it * 256;
                int kk = q >> 5;
                int nn = (q & 31) * 4;
                floatx4 f = *reinterpret_cast<const floatx4*>(W + (size_t)(k0 + kk) * N + n0 + nn);
                Bs[(nn + 0) * LDT + kk] = f2bf(f.x);
                Bs[(nn + 1) * LDT + kk] = f2bf(f.y);
                Bs[(nn + 2) * LDT + kk] = f2bf(f.z);
                Bs[(nn + 3) * LDT + kk] = f2bf(f.w);
            }
        }
        __syncthreads();

        bf16x8_t av[4], bv[4];
#pragma unroll
        for (int i = 0; i < 4; ++i)
            av[i] = *reinterpret_cast<const bf16x8_t*>(&As[(wm * 64 + i * 16 + lr) * LDT + quad * 8]);
#pragma unroll
        for (int j = 0; j < 4; ++j)
            bv[j] = *reinterpret_cast<const bf16x8_t*>(&Bs[(wn * 64 + j * 16 + lr) * LDT + quad * 8]);

#pragma unroll
        for (int i = 0; i < 4; ++i)
#pragma unroll
            for (int j = 0; j < 4; ++j)
                acc[i][j] = __builtin_amdgcn_mfma_f32_16x16x32_bf16(av[i], bv[j], acc[i][j], 0, 0, 0);

        __syncthreads();
    }

#pragma unroll
    for (int j = 0; j < 4; ++j) {
        int col = n0 + wn * 64 + j * 16 + lr;
        float bj = bias[col];
#pragma unroll
        for (int i = 0; i < 4; ++i) {
            int rbase = m0 + wm * 64 + i * 16 + quad * 4;
#pragma unroll
            for (int r = 0; r < 4; ++r) {
                float v = acc[i][j][r] + bj;
                size_t idx = (size_t)(rbase + r) * ldc + col;
                if (C_F32) ((float*)Cp)[idx] = v;
                else       ((unsigned short*)Cp)[idx] = f2bf(v);
            }
        }
    }
}

// ---------------------------------------------------------------------------
// Tiled neighborhood attention: one block per (b, 64-l-tile, head).
// Stage k/v window (76 rows) + q tile into LDS once; compute logits/softmax/AV
// entirely from LDS; write attn in place to the q-slot (block is the sole
// toucher of its q rows x head-slice; k/v slots never written).
// LDS rows padded to 65 f32 -> odd bank multiplier -> conflict-free reads.
// ---------------------------------------------------------------------------
#define NA_L 4096
#define NA_K 13
#define NA_H 16
#define NA_D 64
#define NA_SCALE 0.125f
#define TL  64
#define WIN 76          // TL + 12
#define KD  65          // padded f32 row

__global__ __launch_bounds__(256) void na1d_tiled_kernel(
    unsigned short* qkv, const float* __restrict__ rpb)
{
    __shared__ float ks[WIN * KD];
    __shared__ float vs[WIN * KD];
    __shared__ float qs[TL * KD];
    __shared__ float wgt[TL][NA_K];

    const int bid = blockIdx.x;
    const int h  = bid & 15;
    const int lt = (bid >> 4) & 63;
    const int b  = bid >> 10;
    const int l0 = lt * TL;
    const int rs = l0 - 6;

    const int t = threadIdx.x;
    const size_t rowbase = (size_t)b * NA_L;

    // ---- phase 1: stage q (scaled) + k/v window ----
    {
        int r  = t >> 2;                 // 0..63
        int c0 = (t & 3) * 16;
        const unsigned short* src = qkv + (rowbase + l0 + r) * 3072 + h * 64 + c0;
        uint4 u0 = *reinterpret_cast<const uint4*>(src);
        uint4 u1 = *reinterpret_cast<const uint4*>(src + 8);
        unpack8(u0, &qs[r * KD + c0], NA_SCALE);
        unpack8(u1, &qs[r * KD + c0 + 8], NA_SCALE);
    }
    for (int idx = t; idx < WIN * 8; idx += 256) {   // 608 16B-chunks
        int r  = idx >> 3;
        int c0 = (idx & 7) * 8;
        int gr = rs + r;
        gr = gr < 0 ? 0 : (gr > NA_L - 1 ? NA_L - 1 : gr);
        const unsigned short* kp = qkv + (rowbase + gr) * 3072 + 1024 + h * 64 + c0;
        uint4 uk = *reinterpret_cast<const uint4*>(kp);
        uint4 uv = *reinterpret_cast<const uint4*>(kp + 1024);
        unpack8(uk, &ks[r * KD + c0], 1.f);
        unpack8(uv, &vs[r * KD + c0], 1.f);
    }
    __syncthreads();

    // ---- phase 2: logits. wave w handles j = 4w..4w+3 for its lane's l ----
    {
        const int l  = t & 63;
        const int jb = (t >> 6) * 4;
        int ig = l0 + l;
        int ni = ig - 6;
        if (ni < 0) ni = 0;
        if (ni > NA_L - NA_K) ni = NA_L - NA_K;
        int rid = ni - rs;                    // 0..57 (rid+jb+3 <= 72 < 76)
        int pi  = ni - ig + 12;
        const float* qr  = &qs[l * KD];
        const float* kp0 = &ks[(rid + jb) * KD];
        float s0 = 0.f, s1 = 0.f, s2 = 0.f, s3 = 0.f;
#pragma unroll
        for (int d = 0; d < NA_D; ++d) {
            float qv = qr[d];
            s0 += qv * kp0[d];
            s1 += qv * kp0[KD + d];
            s2 += qv * kp0[2 * KD + d];
            s3 += qv * kp0[3 * KD + d];
        }
        const float* rp = rpb + h * 25 + pi;
        if (jb + 0 < NA_K) wgt[l][jb + 0] = s0 + rp[jb + 0];
        if (jb + 1 < NA_K) wgt[l][jb + 1] = s1 + rp[jb + 1];
        if (jb + 2 < NA_K) wgt[l][jb + 2] = s2 + rp[jb + 2];
        if (jb + 3 < NA_K) wgt[l][jb + 3] = s3 + rp[jb + 3];
    }
    __syncthreads();

    // ---- phase 3: softmax per l ----
    if (t < TL) {
        float m = -1e30f;
#pragma unroll
        for (int j = 0; j < NA_K; ++j) m = fmaxf(m, wgt[t][j]);
        float sum = 0.f;
#pragma unroll
        for (int j = 0; j < NA_K; ++j) {
            float e = expf(wgt[t][j] - m);
            wgt[t][j] = e;
            sum += e;
        }
        float inv = 1.f / sum;
#pragma unroll
        for (int j = 0; j < NA_K; ++j) wgt[t][j] *= inv;
    }
    __syncthreads();

    // ---- phase 4: AV. thread (l, 16-d chunk) ----
    {
        const int l  = t & 63;
        const int d0 = (t >> 6) * 16;
        int ig = l0 + l;
        int ni = ig - 6;
        if (ni < 0) ni = 0;
        if (ni > NA_L - NA_K) ni = NA_L - NA_K;
        int rid = ni - rs;
        float o[16];
#pragma unroll
        for (int d = 0; d < 16; ++d) o[d] = 0.f;
#pragma unroll
        for (int j = 0; j < NA_K; ++j) {
            float w = wgt[l][j];
            const float* vr = &vs[(rid + j) * KD + d0];
#pragma unroll
            for (int d = 0; d < 16; ++d) o[d] += w * vr[d];
        }
        unsigned short* dst = qkv + (rowbase + ig) * 3072 + h * 64 + d0;
        uint4 p0, p1;
        p0.x = (unsigned int)f2bf(o[0])  | ((unsigned int)f2bf(o[1])  << 16);
        p0.y = (unsigned int)f2bf(o[2])  | ((unsigned int)f2bf(o[3])  << 16);
        p0.z = (unsigned int)f2bf(o[4])  | ((unsigned int)f2bf(o[5])  << 16);
        p0.w = (unsigned int)f2bf(o[6])  | ((unsigned int)f2bf(o[7])  << 16);
        p1.x = (unsigned int)f2bf(o[8])  | ((unsigned int)f2bf(o[9])  << 16);
        p1.y = (unsigned int)f2bf(o[10]) | ((unsigned int)f2bf(o[11]) << 16);
        p1.z = (unsigned int)f2bf(o[12]) | ((unsigned int)f2bf(o[13]) << 16);
        p1.w = (unsigned int)f2bf(o[14]) | ((unsigned int)f2bf(o[15]) << 16);
        *reinterpret_cast<uint4*>(dst)     = p0;
        *reinterpret_cast<uint4*>(dst + 8) = p1;
    }
}

// ---------------------------------------------------------------------------
extern "C" void kernel_launch(void* const* d_in, const int* in_sizes, int n_in,
                              void* d_out, int out_size, void* d_ws, size_t ws_size,
                              hipStream_t stream)
{
    const float* x      = (const float*)d_in[0];
    const float* w_qkv  = (const float*)d_in[1];
    const float* b_qkv  = (const float*)d_in[2];
    const float* rpb    = (const float*)d_in[3];
    const float* w_proj = (const float*)d_in[4];
    const float* b_proj = (const float*)d_in[5];
    float* out = (float*)d_out;

    const int M  = 4 * 4096;   // 16384
    const int K  = 1024;
    const int N1 = 3072;
    const int N2 = 1024;

    unsigned short* qkv = (unsigned short*)d_ws;              // 96 MiB
    unsigned short* Wt1 = qkv + (size_t)M * N1;               // 6 MiB
    unsigned short* Wt2 = Wt1 + (size_t)N1 * K;               // 2 MiB
    unsigned short* xb  = Wt2 + (size_t)N2 * K;               // 32 MiB
    size_t need_mid  = ((size_t)M * N1 + (size_t)N1 * K + (size_t)N2 * K) * 2;
    size_t need_fast = need_mid + (size_t)M * K * 2;

    const int na_grid = 4 * (NA_L / TL) * NA_H;               // 4096

    if (ws_size >= need_fast) {
        convert_f32_bf16<<<dim3(M * K / (256 * 8)), 256, 0, stream>>>(x, xb);
        transpose_f32_to_bf16<<<dim3(N1 / 32, K / 32), 256, 0, stream>>>(w_qkv, Wt1, K, N1);
        transpose_f32_to_bf16<<<dim3(N2 / 32, K / 32), 256, 0, stream>>>(w_proj, Wt2, K, N2);
        gemm_lds_kernel<false><<<dim3(N1 / BN, M / BM), 256, 0, stream>>>(
            xb, Wt1, b_qkv, qkv, N1, K, K, N1);
        na1d_tiled_kernel<<<dim3(na_grid), 256, 0, stream>>>(qkv, rpb);
        gemm_lds_kernel<true><<<dim3(N2 / BN, M / BM), 256, 0, stream>>>(
            qkv, Wt2, b_proj, out, N2, K, N1, N2);
    } else if (ws_size >= need_mid) {
        transpose_f32_to_bf16<<<dim3(N1 / 32, K / 32), 256, 0, stream>>>(w_qkv, Wt1, K, N1);
        transpose_f32_to_bf16<<<dim3(N2 / 32, K / 32), 256, 0, stream>>>(w_proj, Wt2, K, N2);
        gemm_bias_kernel<true, false, true><<<dim3(N1 / BN, M / BM), 256, 0, stream>>>(
            x, Wt1, b_qkv, qkv, N1, K, K, N1);
        na1d_tiled_kernel<<<dim3(na_grid), 256, 0, stream>>>(qkv, rpb);
        gemm_bias_kernel<false, true, true><<<dim3(N2 / BN, M / BM), 256, 0, stream>>>(
            qkv, Wt2, b_proj, out, N2, K, N1, N2);
    } else {
        gemm_bias_kernel<true, false, false><<<dim3(N1 / BN, M / BM), 256, 0, stream>>>(
            x, w_qkv, b_qkv, qkv, N1, K, K, N1);
        na1d_tiled_kernel<<<dim3(na_grid), 256, 0, stream>>>(qkv, rpb);
        gemm_bias_kernel<false, true, false><<<dim3(N2 / BN, M / BM), 256, 0, stream>>>(
            qkv, w_proj, b_proj, out, N2, K, N1, N2);
    }
}

// Round 7
// 405.500 us; speedup vs baseline: 1.9951x; 1.0789x over previous
//
#include <hip/hip_runtime.h>

typedef __bf16 bf16x8_t __attribute__((ext_vector_type(8)));
typedef float  f32x4_t  __attribute__((ext_vector_type(4)));
typedef float  floatx4  __attribute__((ext_vector_type(4)));
typedef unsigned short ushortx4 __attribute__((ext_vector_type(4)));

__device__ __forceinline__ float bf2f(unsigned short u) {
    union { unsigned int i; float f; } c; c.i = ((unsigned int)u) << 16; return c.f;
}
__device__ __forceinline__ unsigned short f2bf(float f) {
    union { float f; unsigned int i; } c; c.f = f;
    unsigned int u = c.i;
    u += 0x7fffu + ((u >> 16) & 1u);   // RNE
    return (unsigned short)(u >> 16);
}
__device__ __forceinline__ void unpack8(uint4 u, float* dst, float sc) {
    dst[0] = bf2f((unsigned short)(u.x & 0xffff)) * sc;
    dst[1] = bf2f((unsigned short)(u.x >> 16)) * sc;
    dst[2] = bf2f((unsigned short)(u.y & 0xffff)) * sc;
    dst[3] = bf2f((unsigned short)(u.y >> 16)) * sc;
    dst[4] = bf2f((unsigned short)(u.z & 0xffff)) * sc;
    dst[5] = bf2f((unsigned short)(u.z >> 16)) * sc;
    dst[6] = bf2f((unsigned short)(u.w & 0xffff)) * sc;
    dst[7] = bf2f((unsigned short)(u.w >> 16)) * sc;
}

// async global->LDS, 16 B per lane; lds dest = wave-uniform base + lane*16
__device__ __forceinline__ void load_lds16(const unsigned short* g, unsigned short* l) {
    __builtin_amdgcn_global_load_lds(
        (const __attribute__((address_space(1))) unsigned int*)g,
        (__attribute__((address_space(3))) unsigned int*)l, 16, 0, 0);
}

// ---------------------------------------------------------------------------
// x (f32) -> bf16, 8 elems/thread
// ---------------------------------------------------------------------------
__global__ __launch_bounds__(256) void convert_f32_bf16(
    const float* __restrict__ x, unsigned short* __restrict__ xb)
{
    size_t i = ((size_t)blockIdx.x * 256 + threadIdx.x) * 8;
    floatx4 a = *reinterpret_cast<const floatx4*>(x + i);
    floatx4 b = *reinterpret_cast<const floatx4*>(x + i + 4);
    uint4 o;
    o.x = (unsigned int)f2bf(a.x) | ((unsigned int)f2bf(a.y) << 16);
    o.y = (unsigned int)f2bf(a.z) | ((unsigned int)f2bf(a.w) << 16);
    o.z = (unsigned int)f2bf(b.x) | ((unsigned int)f2bf(b.y) << 16);
    o.w = (unsigned int)f2bf(b.z) | ((unsigned int)f2bf(b.w) << 16);
    *reinterpret_cast<uint4*>(xb + i) = o;
}

// ---------------------------------------------------------------------------
// Weight prep: Wt[n][k] (bf16) = W[k][n] (f32). 32x32 LDS-tiled transpose.
// ---------------------------------------------------------------------------
__global__ __launch_bounds__(256) void transpose_f32_to_bf16(
    const float* __restrict__ W, unsigned short* __restrict__ Wt,
    int Kdim, int Ndim)
{
    __shared__ float tile[32][33];
    const int n0 = blockIdx.x * 32, k0 = blockIdx.y * 32;
    const int tx = threadIdx.x & 31, ty = threadIdx.x >> 5;   // ty 0..7
#pragma unroll
    for (int r = 0; r < 4; ++r) {
        int k = ty + r * 8;
        tile[k][tx] = W[(size_t)(k0 + k) * Ndim + n0 + tx];
    }
    __syncthreads();
#pragma unroll
    for (int r = 0; r < 4; ++r) {
        int n = ty + r * 8;
        Wt[(size_t)(n0 + n) * Kdim + k0 + tx] = f2bf(tile[tx][n]);
    }
}

// ---------------------------------------------------------------------------
// m97-style GEMM with XOR-swizzled LDS (R6-proven: SQ_LDS_BANK_CONFLICT = 0).
// ---------------------------------------------------------------------------
#define BM 128
#define BN 128
#define BK 32

template<bool C_F32>
__global__ __launch_bounds__(256) void gemm_lds_kernel(
    const unsigned short* __restrict__ A, const unsigned short* __restrict__ Wt,
    const float* __restrict__ bias, void* __restrict__ Cp,
    int N, int K, int lda, int ldc)
{
    __shared__ __align__(16) unsigned short As[BM * BK];
    __shared__ __align__(16) unsigned short Bs[BN * BK];

    const int tid  = threadIdx.x;
    const int lane = tid & 63;
    const int wid  = tid >> 6;       // 0..3
    const int wm   = wid >> 1;       // 0..1
    const int wn   = wid & 1;        // 0..1
    const int quad = lane >> 4;      // 0..3
    const int lr   = lane & 15;      // 0..15

    const int m0 = blockIdx.y * BM;
    const int n0 = blockIdx.x * BN;

    const int s_row = tid >> 2;                                  // 0..63
    const int c_sw  = ((tid & 3) ^ ((tid >> 3) & 3)) * 8;        // swizzled source chunk
    const int xq    = (quad ^ ((lr >> 1) & 3)) * 8;              // swizzled read chunk
    unsigned short* ldsA = As + wid * 512;
    unsigned short* ldsB = Bs + wid * 512;

    f32x4_t acc[4][4];
#pragma unroll
    for (int i = 0; i < 4; ++i)
#pragma unroll
        for (int j = 0; j < 4; ++j)
            acc[i][j] = (f32x4_t){0.f, 0.f, 0.f, 0.f};

    for (int k0 = 0; k0 < K; k0 += BK) {
#pragma unroll
        for (int r = 0; r < 2; ++r) {
            load_lds16(A  + (size_t)(m0 + s_row + r * 64) * lda + k0 + c_sw, ldsA + r * 2048);
            load_lds16(Wt + (size_t)(n0 + s_row + r * 64) * K   + k0 + c_sw, ldsB + r * 2048);
        }
        __syncthreads();

        bf16x8_t av[4], bv[4];
#pragma unroll
        for (int i = 0; i < 4; ++i)
            av[i] = *reinterpret_cast<const bf16x8_t*>(&As[(wm * 64 + i * 16 + lr) * BK + xq]);
#pragma unroll
        for (int j = 0; j < 4; ++j)
            bv[j] = *reinterpret_cast<const bf16x8_t*>(&Bs[(wn * 64 + j * 16 + lr) * BK + xq]);

#pragma unroll
        for (int i = 0; i < 4; ++i)
#pragma unroll
            for (int j = 0; j < 4; ++j)
                acc[i][j] = __builtin_amdgcn_mfma_f32_16x16x32_bf16(av[i], bv[j], acc[i][j], 0, 0, 0);

        __syncthreads();
    }

#pragma unroll
    for (int j = 0; j < 4; ++j) {
        int col = n0 + wn * 64 + j * 16 + lr;
        float bj = bias[col];
#pragma unroll
        for (int i = 0; i < 4; ++i) {
            int rbase = m0 + wm * 64 + i * 16 + quad * 4;
#pragma unroll
            for (int r = 0; r < 4; ++r) {
                float v = acc[i][j][r] + bj;
                size_t idx = (size_t)(rbase + r) * ldc + col;
                if (C_F32) ((float*)Cp)[idx] = v;
                else       ((unsigned short*)Cp)[idx] = f2bf(v);
            }
        }
    }
}

// ---------------------------------------------------------------------------
// Fallback GEMM (R3/R4-proven): padded LDS, regular staging.
// ---------------------------------------------------------------------------
#define LDT 40

template<bool A_F32, bool C_F32, bool BT>
__global__ __launch_bounds__(256) void gemm_bias_kernel(
    const void* __restrict__ Ap, const void* __restrict__ Wp,
    const float* __restrict__ bias, void* __restrict__ Cp,
    int N, int K, int lda, int ldc)
{
    __shared__ __align__(16) unsigned short As[BM * LDT];
    __shared__ __align__(16) unsigned short Bs[BN * LDT];

    const int tid  = threadIdx.x;
    const int lane = tid & 63;
    const int wid  = tid >> 6;
    const int wm   = wid >> 1;
    const int wn   = wid & 1;
    const int quad = lane >> 4;
    const int lr   = lane & 15;

    const int m0 = blockIdx.y * BM;
    const int n0 = blockIdx.x * BN;

    f32x4_t acc[4][4];
#pragma unroll
    for (int i = 0; i < 4; ++i)
#pragma unroll
        for (int j = 0; j < 4; ++j)
            acc[i][j] = (f32x4_t){0.f, 0.f, 0.f, 0.f};

    for (int k0 = 0; k0 < K; k0 += BK) {
        if (A_F32) {
            const float* A = (const float*)Ap;
#pragma unroll
            for (int it = 0; it < 4; ++it) {
                int q   = tid + it * 256;
                int row = q >> 3;
                int col = (q & 7) * 4;
                floatx4 f = *reinterpret_cast<const floatx4*>(A + (size_t)(m0 + row) * lda + k0 + col);
                ushortx4 s;
                s.x = f2bf(f.x); s.y = f2bf(f.y); s.z = f2bf(f.z); s.w = f2bf(f.w);
                *reinterpret_cast<ushortx4*>(&As[row * LDT + col]) = s;
            }
        } else {
            const unsigned short* A = (const unsigned short*)Ap;
            int a_row = tid >> 2;
            int a_col = (tid & 3) * 8;
#pragma unroll
            for (int r = 0; r < 2; ++r) {
                int row = a_row + r * 64;
                uint4 u = *reinterpret_cast<const uint4*>(A + (size_t)(m0 + row) * lda + k0 + a_col);
                *reinterpret_cast<uint4*>(&As[row * LDT + a_col]) = u;
            }
        }
        if (BT) {
            const unsigned short* Wt = (const unsigned short*)Wp;
            int b_row = tid >> 2;
            int b_col = (tid & 3) * 8;
#pragma unroll
            for (int r = 0; r < 2; ++r) {
                int n = b_row + r * 64;
                uint4 u = *reinterpret_cast<const uint4*>(Wt + (size_t)(n0 + n) * K + k0 + b_col);
                *reinterpret_cast<uint4*>(&Bs[n * LDT + b_col]) = u;
            }
        } else {
            const float* W = (const float*)Wp;
#pragma unroll
            for (int it = 0; it < 4; ++it) {
                int q  = tid + it * 256;
                int kk = q >> 5;
                int nn = (q & 31) * 4;
                floatx4 f = *reinterpret_cast<const floatx4*>(W + (size_t)(k0 + kk) * N + n0 + nn);
                Bs[(nn + 0) * LDT + kk] = f2bf(f.x);
                Bs[(nn + 1) * LDT + kk] = f2bf(f.y);
                Bs[(nn + 2) * LDT + kk] = f2bf(f.z);
                Bs[(nn + 3) * LDT + kk] = f2bf(f.w);
            }
        }
        __syncthreads();

        bf16x8_t av[4], bv[4];
#pragma unroll
        for (int i = 0; i < 4; ++i)
            av[i] = *reinterpret_cast<const bf16x8_t*>(&As[(wm * 64 + i * 16 + lr) * LDT + quad * 8]);
#pragma unroll
        for (int j = 0; j < 4; ++j)
            bv[j] = *reinterpret_cast<const bf16x8_t*>(&Bs[(wn * 64 + j * 16 + lr) * LDT + quad * 8]);

#pragma unroll
        for (int i = 0; i < 4; ++i)
#pragma unroll
            for (int j = 0; j < 4; ++j)
                acc[i][j] = __builtin_amdgcn_mfma_f32_16x16x32_bf16(av[i], bv[j], acc[i][j], 0, 0, 0);

        __syncthreads();
    }

#pragma unroll
    for (int j = 0; j < 4; ++j) {
        int col = n0 + wn * 64 + j * 16 + lr;
        float bj = bias[col];
#pragma unroll
        for (int i = 0; i < 4; ++i) {
            int rbase = m0 + wm * 64 + i * 16 + quad * 4;
#pragma unroll
            for (int r = 0; r < 4; ++r) {
                float v = acc[i][j][r] + bj;
                size_t idx = (size_t)(rbase + r) * ldc + col;
                if (C_F32) ((float*)Cp)[idx] = v;
                else       ((unsigned short*)Cp)[idx] = f2bf(v);
            }
        }
    }
}

// ---------------------------------------------------------------------------
// Tiled neighborhood attention v2: one block per (b, 64-l-tile, head).
// Same math as R6 (passed); changes are scheduling/layout only:
//  - global loads PREFETCHED into registers (4-6 uint4 in flight per thread)
//    before any unpack -> restores memory-level parallelism.
//  - LDS rows padded to KD=68 floats (16B-aligned, bank base (4r+d)%32) so
//    ALL LDS traffic is float4 b128 at the LDS bandwidth floor.
// ---------------------------------------------------------------------------
#define NA_L 4096
#define NA_K 13
#define NA_H 16
#define NA_D 64
#define NA_SCALE 0.125f
#define TL  64
#define WIN 76          // TL + 12
#define KD  68          // padded f32 row (17 float4 chunks)

__global__ __launch_bounds__(256) void na1d_tiled_kernel(
    unsigned short* qkv, const float* __restrict__ rpb)
{
    __shared__ __align__(16) float ks[WIN * KD];
    __shared__ __align__(16) float vs[WIN * KD];
    __shared__ __align__(16) float qs[TL * KD];
    __shared__ float wgt[TL][NA_K];

    const int bid = blockIdx.x;
    const int h  = bid & 15;
    const int lt = (bid >> 4) & 63;
    const int b  = bid >> 10;
    const int l0 = lt * TL;
    const int rs = l0 - 6;

    const int t = threadIdx.x;
    const size_t rowbase = (size_t)b * NA_L;

    // ---- phase 1: prefetch q + k/v window, then unpack to LDS ----
    {
        // q: thread covers 16 dims of row (t>>2)
        const int qr = t >> 2;
        const int qc = (t & 3) * 16;
        const unsigned short* qsrc = qkv + (rowbase + l0 + qr) * 3072 + h * 64 + qc;
        uint4 q0 = *reinterpret_cast<const uint4*>(qsrc);
        uint4 q1 = *reinterpret_cast<const uint4*>(qsrc + 8);

        // k/v: chunk (row r, 8 dims at cc); rows r0, r0+32, r0+64(t<96)
        const int r0 = t >> 3;            // 0..31
        const int cc = (t & 7) * 8;
        int g0 = rs + r0;      g0 = g0 < 0 ? 0 : (g0 > NA_L - 1 ? NA_L - 1 : g0);
        int g1 = rs + r0 + 32; g1 = g1 < 0 ? 0 : (g1 > NA_L - 1 ? NA_L - 1 : g1);
        const unsigned short* p0 = qkv + (rowbase + g0) * 3072 + 1024 + h * 64 + cc;
        const unsigned short* p1 = qkv + (rowbase + g1) * 3072 + 1024 + h * 64 + cc;
        uint4 k0 = *reinterpret_cast<const uint4*>(p0);
        uint4 v0 = *reinterpret_cast<const uint4*>(p0 + 1024);
        uint4 k1 = *reinterpret_cast<const uint4*>(p1);
        uint4 v1 = *reinterpret_cast<const uint4*>(p1 + 1024);
        uint4 k2, v2;
        if (t < 96) {
            int g2 = rs + r0 + 64; g2 = g2 < 0 ? 0 : (g2 > NA_L - 1 ? NA_L - 1 : g2);
            const unsigned short* p2 = qkv + (rowbase + g2) * 3072 + 1024 + h * 64 + cc;
            k2 = *reinterpret_cast<const uint4*>(p2);
            v2 = *reinterpret_cast<const uint4*>(p2 + 1024);
        }

        unpack8(q0, &qs[qr * KD + qc], NA_SCALE);
        unpack8(q1, &qs[qr * KD + qc + 8], NA_SCALE);
        unpack8(k0, &ks[r0 * KD + cc], 1.f);
        unpack8(v0, &vs[r0 * KD + cc], 1.f);
        unpack8(k1, &ks[(r0 + 32) * KD + cc], 1.f);
        unpack8(v1, &vs[(r0 + 32) * KD + cc], 1.f);
        if (t < 96) {
            unpack8(k2, &ks[(r0 + 64) * KD + cc], 1.f);
            unpack8(v2, &vs[(r0 + 64) * KD + cc], 1.f);
        }
    }
    __syncthreads();

    // ---- phase 2: logits; wave jb handles j = 4jb..4jb+3 for lane's l ----
    {
        const int l  = t & 63;
        const int jb = (t >> 6) * 4;
        int ig = l0 + l;
        int ni = ig - 6;
        if (ni < 0) ni = 0;
        if (ni > NA_L - NA_K) ni = NA_L - NA_K;
        int rid = ni - rs;                    // 0..57
        int pi  = ni - ig + 12;
        const floatx4* qr = reinterpret_cast<const floatx4*>(&qs[l * KD]);
        const floatx4* k0 = reinterpret_cast<const floatx4*>(&ks[(rid + jb + 0) * KD]);
        const floatx4* k1 = reinterpret_cast<const floatx4*>(&ks[(rid + jb + 1) * KD]);
        const floatx4* k2 = reinterpret_cast<const floatx4*>(&ks[(rid + jb + 2) * KD]);
        const floatx4* k3 = reinterpret_cast<const floatx4*>(&ks[(rid + jb + 3) * KD]);
        floatx4 a0 = {0,0,0,0}, a1 = {0,0,0,0}, a2 = {0,0,0,0}, a3 = {0,0,0,0};
#pragma unroll
        for (int c = 0; c < 16; ++c) {
            floatx4 qv = qr[c];
            a0 += qv * k0[c];
            a1 += qv * k1[c];
            a2 += qv * k2[c];
            a3 += qv * k3[c];
        }
        float s0 = a0.x + a0.y + a0.z + a0.w;
        float s1 = a1.x + a1.y + a1.z + a1.w;
        float s2 = a2.x + a2.y + a2.z + a2.w;
        float s3 = a3.x + a3.y + a3.z + a3.w;
        const float* rp = rpb + h * 25 + pi;
        if (jb + 0 < NA_K) wgt[l][jb + 0] = s0 + rp[jb + 0];
        if (jb + 1 < NA_K) wgt[l][jb + 1] = s1 + rp[jb + 1];
        if (jb + 2 < NA_K) wgt[l][jb + 2] = s2 + rp[jb + 2];
        if (jb + 3 < NA_K) wgt[l][jb + 3] = s3 + rp[jb + 3];
    }
    __syncthreads();

    // ---- phase 3: softmax per l ----
    if (t < TL) {
        float m = -1e30f;
#pragma unroll
        for (int j = 0; j < NA_K; ++j) m = fmaxf(m, wgt[t][j]);
        float sum = 0.f;
#pragma unroll
        for (int j = 0; j < NA_K; ++j) {
            float e = expf(wgt[t][j] - m);
            wgt[t][j] = e;
            sum += e;
        }
        float inv = 1.f / sum;
#pragma unroll
        for (int j = 0; j < NA_K; ++j) wgt[t][j] *= inv;
    }
    __syncthreads();

    // ---- phase 4: AV. thread (l, 16-d chunk), float4 reads ----
    {
        const int l  = t & 63;
        const int d0 = (t >> 6) * 16;
        int ig = l0 + l;
        int ni = ig - 6;
        if (ni < 0) ni = 0;
        if (ni > NA_L - NA_K) ni = NA_L - NA_K;
        int rid = ni - rs;
        floatx4 o0 = {0,0,0,0}, o1 = {0,0,0,0}, o2 = {0,0,0,0}, o3 = {0,0,0,0};
#pragma unroll
        for (int j = 0; j < NA_K; ++j) {
            float w = wgt[l][j];
            const floatx4* vr = reinterpret_cast<const floatx4*>(&vs[(rid + j) * KD + d0]);
            o0 += w * vr[0];
            o1 += w * vr[1];
            o2 += w * vr[2];
            o3 += w * vr[3];
        }
        unsigned short* dst = qkv + (rowbase + ig) * 3072 + h * 64 + d0;
        uint4 p0, p1;
        p0.x = (unsigned int)f2bf(o0.x) | ((unsigned int)f2bf(o0.y) << 16);
        p0.y = (unsigned int)f2bf(o0.z) | ((unsigned int)f2bf(o0.w) << 16);
        p0.z = (unsigned int)f2bf(o1.x) | ((unsigned int)f2bf(o1.y) << 16);
        p0.w = (unsigned int)f2bf(o1.z) | ((unsigned int)f2bf(o1.w) << 16);
        p1.x = (unsigned int)f2bf(o2.x) | ((unsigned int)f2bf(o2.y) << 16);
        p1.y = (unsigned int)f2bf(o2.z) | ((unsigned int)f2bf(o2.w) << 16);
        p1.z = (unsigned int)f2bf(o3.x) | ((unsigned int)f2bf(o3.y) << 16);
        p1.w = (unsigned int)f2bf(o3.z) | ((unsigned int)f2bf(o3.w) << 16);
        *reinterpret_cast<uint4*>(dst)     = p0;
        *reinterpret_cast<uint4*>(dst + 8) = p1;
    }
}

// ---------------------------------------------------------------------------
extern "C" void kernel_launch(void* const* d_in, const int* in_sizes, int n_in,
                              void* d_out, int out_size, void* d_ws, size_t ws_size,
                              hipStream_t stream)
{
    const float* x      = (const float*)d_in[0];
    const float* w_qkv  = (const float*)d_in[1];
    const float* b_qkv  = (const float*)d_in[2];
    const float* rpb    = (const float*)d_in[3];
    const float* w_proj = (const float*)d_in[4];
    const float* b_proj = (const float*)d_in[5];
    float* out = (float*)d_out;

    const int M  = 4 * 4096;   // 16384
    const int K  = 1024;
    const int N1 = 3072;
    const int N2 = 1024;

    unsigned short* qkv = (unsigned short*)d_ws;              // 96 MiB
    unsigned short* Wt1 = qkv + (size_t)M * N1;               // 6 MiB
    unsigned short* Wt2 = Wt1 + (size_t)N1 * K;               // 2 MiB
    unsigned short* xb  = Wt2 + (size_t)N2 * K;               // 32 MiB
    size_t need_mid  = ((size_t)M * N1 + (size_t)N1 * K + (size_t)N2 * K) * 2;
    size_t need_fast = need_mid + (size_t)M * K * 2;

    const int na_grid = 4 * (NA_L / TL) * NA_H;               // 4096

    if (ws_size >= need_fast) {
        convert_f32_bf16<<<dim3(M * K / (256 * 8)), 256, 0, stream>>>(x, xb);
        transpose_f32_to_bf16<<<dim3(N1 / 32, K / 32), 256, 0, stream>>>(w_qkv, Wt1, K, N1);
        transpose_f32_to_bf16<<<dim3(N2 / 32, K / 32), 256, 0, stream>>>(w_proj, Wt2, K, N2);
        gemm_lds_kernel<false><<<dim3(N1 / BN, M / BM), 256, 0, stream>>>(
            xb, Wt1, b_qkv, qkv, N1, K, K, N1);
        na1d_tiled_kernel<<<dim3(na_grid), 256, 0, stream>>>(qkv, rpb);
        gemm_lds_kernel<true><<<dim3(N2 / BN, M / BM), 256, 0, stream>>>(
            qkv, Wt2, b_proj, out, N2, K, N1, N2);
    } else if (ws_size >= need_mid) {
        transpose_f32_to_bf16<<<dim3(N1 / 32, K / 32), 256, 0, stream>>>(w_qkv, Wt1, K, N1);
        transpose_f32_to_bf16<<<dim3(N2 / 32, K / 32), 256, 0, stream>>>(w_proj, Wt2, K, N2);
        gemm_bias_kernel<true, false, true><<<dim3(N1 / BN, M / BM), 256, 0, stream>>>(
            x, Wt1, b_qkv, qkv, N1, K, K, N1);
        na1d_tiled_kernel<<<dim3(na_grid), 256, 0, stream>>>(qkv, rpb);
        gemm_bias_kernel<false, true, true><<<dim3(N2 / BN, M / BM), 256, 0, stream>>>(
            qkv, Wt2, b_proj, out, N2, K, N1, N2);
    } else {
        gemm_bias_kernel<true, false, false><<<dim3(N1 / BN, M / BM), 256, 0, stream>>>(
            x, w_qkv, b_qkv, qkv, N1, K, K, N1);
        na1d_tiled_kernel<<<dim3(na_grid), 256, 0, stream>>>(qkv, rpb);
        gemm_bias_kernel<false, true, false><<<dim3(N2 / BN, M / BM), 256, 0, stream>>>(
            qkv, w_proj, b_proj, out, N2, K, N1, N2);
    }
}